// Round 4
// baseline (647.132 us; speedup 1.0000x reference)
//
#include <hip/hip_runtime.h>

#define RNN_T 2048
#define RNN_B 4096
#define BLK 4              // timesteps per x block (20 floats = 5 float4)
#define NBLK (RNN_T / BLK) // 512

// tanh with pre-scaled argument: zs = 2*log2(e)*z ; tanh(z) = 1 - 2/(1 + 2^zs)
__device__ __forceinline__ float tanh_pre(float zs) {
    float e = __builtin_amdgcn_exp2f(zs);
    float r = __builtin_amdgcn_rcpf(e + 1.0f);
    return fmaf(-2.0f, r, 1.0f);
}

// Broadcast lane (group16_base | K)'s value to all 16 lanes of the group.
// ds_swizzle BitMode: src = (lane & and) | or ; offset = (xor<<10)|(or<<5)|and.
template <int K>
__device__ __forceinline__ float bcast16(float v) {
    return __int_as_float(__builtin_amdgcn_ds_swizzle(__float_as_int(v), (K << 5) | 16));
}

template <int IDX>
__device__ __forceinline__ float getf(const float4 (&b)[5]) {
    constexpr int q = IDX >> 2, r = IDX & 3;
    if constexpr (r == 0) return b[q].x;
    else if constexpr (r == 1) return b[q].y;
    else if constexpr (r == 2) return b[q].z;
    else return b[q].w;
}

// One timestep of TWO independent chains (same weights), interleaved for ILP.
template <int U>
__device__ __forceinline__ void step_pair(const float4 (&bA)[5], const float4 (&bB)[5],
                                          float& hA, float& hB,
                                          const float (&W1)[5], const float (&W2)[9],
                                          const float bb) {
    float a0 = bcast16<0>(hA), b0 = bcast16<0>(hB);
    float a1 = bcast16<1>(hA), b1 = bcast16<1>(hB);
    float a2 = bcast16<2>(hA), b2 = bcast16<2>(hB);
    float a3 = bcast16<3>(hA), b3 = bcast16<3>(hB);
    float a4 = bcast16<4>(hA), b4 = bcast16<4>(hB);
    float a5 = bcast16<5>(hA), b5 = bcast16<5>(hB);
    float a6 = bcast16<6>(hA), b6 = bcast16<6>(hB);
    float a7 = bcast16<7>(hA), b7 = bcast16<7>(hB);
    float a8 = bcast16<8>(hA), b8 = bcast16<8>(hB);

    // x parts (independent of broadcasts -> fill swizzle latency)
    float xA = fmaf(W1[0], getf<U * 5 + 0>(bA), bb);
    float xB = fmaf(W1[0], getf<U * 5 + 0>(bB), bb);
    xA = fmaf(W1[1], getf<U * 5 + 1>(bA), xA);
    xB = fmaf(W1[1], getf<U * 5 + 1>(bB), xB);
    xA = fmaf(W1[2], getf<U * 5 + 2>(bA), xA);
    xB = fmaf(W1[2], getf<U * 5 + 2>(bB), xB);
    xA = fmaf(W1[3], getf<U * 5 + 3>(bA), xA);
    xB = fmaf(W1[3], getf<U * 5 + 3>(bB), xB);
    xA = fmaf(W1[4], getf<U * 5 + 4>(bA), xA);
    xB = fmaf(W1[4], getf<U * 5 + 4>(bB), xB);

    // h parts, 3 accumulators per chain, chains interleaved
    float pA = W2[0] * a0,        pB = W2[0] * b0;
    float qA = W2[1] * a1,        qB = W2[1] * b1;
    pA = fmaf(W2[2], a2, pA);     pB = fmaf(W2[2], b2, pB);
    qA = fmaf(W2[3], a3, qA);     qB = fmaf(W2[3], b3, qB);
    pA = fmaf(W2[4], a4, pA);     pB = fmaf(W2[4], b4, pB);
    qA = fmaf(W2[5], a5, qA);     qB = fmaf(W2[5], b5, qB);
    pA = fmaf(W2[6], a6, pA);     pB = fmaf(W2[6], b6, pB);
    qA = fmaf(W2[7], a7, qA);     qB = fmaf(W2[7], b7, qB);
    xA = fmaf(W2[8], a8, xA);     xB = fmaf(W2[8], b8, xB);

    hA = tanh_pre((xA + pA) + qA);
    hB = tanh_pre((xB + pB) + qB);
}

__device__ __forceinline__ void loadblk(float4 (&buf)[5], const float* xp, int phys) {
    const float4* q = (const float4*)(xp + phys * (BLK * 5));
#pragma unroll
    for (int v = 0; v < 5; ++v) buf[v] = q[v];
}

template <bool FWD>
__device__ __forceinline__ void proc4_pair(const float4 (&bA)[5], const float4 (&bB)[5],
                                           float& hA, float& hB, const float (&W1)[5],
                                           const float (&W2)[9], const float bb) {
    if constexpr (FWD) {
        step_pair<0>(bA, bB, hA, hB, W1, W2, bb);
        step_pair<1>(bA, bB, hA, hB, W1, W2, bb);
        step_pair<2>(bA, bB, hA, hB, W1, W2, bb);
        step_pair<3>(bA, bB, hA, hB, W1, W2, bb);
    } else {
        step_pair<3>(bA, bB, hA, hB, W1, W2, bb);
        step_pair<2>(bA, bB, hA, hB, W1, W2, bb);
        step_pair<1>(bA, bB, hA, hB, W1, W2, bb);
        step_pair<0>(bA, bB, hA, hB, W1, W2, bb);
    }
}

template <bool FWD>
__device__ __forceinline__ int physOf(int i) {
    if constexpr (FWD) return (i < NBLK - 1) ? i : (NBLK - 1);
    else { int p = NBLK - 1 - i; return (p > 0) ? p : 0; }
}

template <bool FWD>
__device__ __forceinline__ void run_pair(const float* xpA, const float* xpB,
                                         const float (&W1)[5], const float (&W2)[9],
                                         const float bb, float& hA, float& hB) {
    float4 A0[5], A1[5], A2[5], B0[5], B1[5], B2[5];   // 120 VGPRs x-buffering
    hA = 0.0f; hB = 0.0f;
    loadblk(A0, xpA, physOf<FWD>(0)); loadblk(B0, xpB, physOf<FWD>(0));
    loadblk(A1, xpA, physOf<FWD>(1)); loadblk(B1, xpB, physOf<FWD>(1));
#pragma unroll 1
    for (int i = 0; i < NBLK - 2; i += 3) {   // i = 0,3,...,507 -> blocks 0..509
        loadblk(A2, xpA, physOf<FWD>(i + 2)); loadblk(B2, xpB, physOf<FWD>(i + 2));
        proc4_pair<FWD>(A0, B0, hA, hB, W1, W2, bb);
        loadblk(A0, xpA, physOf<FWD>(i + 3)); loadblk(B0, xpB, physOf<FWD>(i + 3));
        proc4_pair<FWD>(A1, B1, hA, hB, W1, W2, bb);
        loadblk(A1, xpA, physOf<FWD>(i + 4)); loadblk(B1, xpB, physOf<FWD>(i + 4));
        proc4_pair<FWD>(A2, B2, hA, hB, W1, W2, bb);
    }
    // tail: blocks 510 (in A0/B0) and 511 (in A1/B1)
    proc4_pair<FWD>(A0, B0, hA, hB, W1, W2, bb);
    proc4_pair<FWD>(A1, B1, hA, hB, W1, W2, bb);
}

// 16 lanes per chain-pair: lane i in [0,9) owns hA[i],hB[i] (chains b, b+2048,
// same direction -> shared weights). 1024 blocks x 64 thr = 1024 waves = 1/SIMD;
// ILP across the two chains fills swizzle/tanh latency.
__global__ __launch_bounds__(64, 1) void rnn1_kernel(
    const float* __restrict__ x,
    const float* __restrict__ w_ih_f, const float* __restrict__ w_hh_f,
    const float* __restrict__ b_ih_f, const float* __restrict__ b_hh_f,
    const float* __restrict__ w_ih_b, const float* __restrict__ w_hh_b,
    const float* __restrict__ b_ih_b, const float* __restrict__ b_hh_b,
    float* __restrict__ y)
{
    const float SC = 2.8853900817779268f; // 2*log2(e)
    const int tid    = threadIdx.x;
    const int group  = tid >> 4;
    const int lane16 = tid & 15;
    const int pair   = blockIdx.x * 4 + group;   // 0..4095
    const int dir    = pair >> 11;               // wave-uniform (2048 % 4 == 0)
    const int b0     = pair & 2047;
    const int b1     = b0 + 2048;
    const int i      = (lane16 < 9) ? lane16 : 8;

    const float* __restrict__ wih = dir ? w_ih_b : w_ih_f;
    const float* __restrict__ whh = dir ? w_hh_b : w_hh_f;
    const float* __restrict__ bih = dir ? b_ih_b : b_ih_f;
    const float* __restrict__ bhh = dir ? b_hh_b : b_hh_f;

    float W1[5], W2[9];
#pragma unroll
    for (int d = 0; d < 5; ++d) W1[d] = wih[i * 5 + d] * SC;
#pragma unroll
    for (int k = 0; k < 9; ++k) W2[k] = whh[i * 9 + k] * SC;
    const float bb = (bih[i] + bhh[i]) * SC;

    const float* xpA = x + (size_t)b0 * (RNN_T * 5);
    const float* xpB = x + (size_t)b1 * (RNN_T * 5);

    float hA, hB;
    if (dir) run_pair<false>(xpA, xpB, W1, W2, bb, hA, hB);
    else     run_pair<true >(xpA, xpB, W1, W2, bb, hA, hB);

    if (lane16 < 9) {
        y[b0 * 18 + dir * 9 + lane16] = hA;
        y[b1 * 18 + dir * 9 + lane16] = hB;
    }
}

__global__ __launch_bounds__(256) void rnn2_kernel(
    const float* __restrict__ y,
    const float* __restrict__ w_ih2, const float* __restrict__ w_hh2,
    const float* __restrict__ b_ih2, const float* __restrict__ b_hh2,
    const float* __restrict__ w_out, const float* __restrict__ b_out,
    float* __restrict__ out)
{
    __shared__ float hist[8][25][32];   // 25.6 KB
    const float SC = 2.8853900817779268f;
    const int bl = threadIdx.x >> 5;    // 0..7 local batch
    const int i  = threadIdx.x & 31;    // component
    const int b  = blockIdx.x * 8 + bl;

    float wr[32];
#pragma unroll
    for (int k = 0; k < 32; ++k) wr[k] = w_hh2[i * 32 + k] * SC;
    const float bias = (b_ih2[i] + b_hh2[i]) * SC;

    // t = 0: input is y, prev hidden is 0
    const float* yb = y + b * 18;
    float z = bias;
#pragma unroll
    for (int k = 0; k < 18; ++k) z = fmaf(w_ih2[i * 18 + k] * SC, yb[k], z);
    hist[bl][0][i] = tanh_pre(z);
    __syncthreads();

    for (int t = 1; t < 25; ++t) {
        float zz = bias;
#pragma unroll
        for (int k = 0; k < 32; ++k) zz = fmaf(wr[k], hist[bl][t - 1][k], zz);
        hist[bl][t][i] = tanh_pre(zz);
        __syncthreads();
    }

    // epilogue: out[b][t][o] = dot(w_out[o], hist[b][t]) + b_out[o]
    for (int e = threadIdx.x; e < 600; e += 256) {
        const int o  = e % 3;
        const int t  = (e / 3) % 25;
        const int b2 = e / 75;
        float acc = b_out[o];
#pragma unroll
        for (int k = 0; k < 32; ++k) acc = fmaf(w_out[o * 32 + k], hist[b2][t][k], acc);
        out[((size_t)(blockIdx.x * 8 + b2) * 25 + t) * 3 + o] = acc;
    }
}

extern "C" void kernel_launch(void* const* d_in, const int* in_sizes, int n_in,
                              void* d_out, int out_size, void* d_ws, size_t ws_size,
                              hipStream_t stream) {
    const float* x      = (const float*)d_in[0];
    const float* w_ih_f = (const float*)d_in[1];
    const float* w_hh_f = (const float*)d_in[2];
    const float* b_ih_f = (const float*)d_in[3];
    const float* b_hh_f = (const float*)d_in[4];
    const float* w_ih_b = (const float*)d_in[5];
    const float* w_hh_b = (const float*)d_in[6];
    const float* b_ih_b = (const float*)d_in[7];
    const float* b_hh_b = (const float*)d_in[8];
    const float* w_ih2  = (const float*)d_in[9];
    const float* w_hh2  = (const float*)d_in[10];
    const float* b_ih2  = (const float*)d_in[11];
    const float* b_hh2  = (const float*)d_in[12];
    const float* w_out  = (const float*)d_in[13];
    const float* b_out  = (const float*)d_in[14];

    float* y = (float*)d_ws;                 // [B][18] intermediate

    rnn1_kernel<<<dim3(1024), dim3(64), 0, stream>>>(
        x, w_ih_f, w_hh_f, b_ih_f, b_hh_f,
        w_ih_b, w_hh_b, b_ih_b, b_hh_b, y);

    rnn2_kernel<<<dim3(RNN_B / 8), dim3(256), 0, stream>>>(
        y, w_ih2, w_hh2, b_ih2, b_hh2, w_out, b_out, (float*)d_out);
}

// Round 5
// 567.799 us; speedup vs baseline: 1.1397x; 1.1397x over previous
//
#include <hip/hip_runtime.h>

#define RNN_T 2048
#define RNN_B 4096
#define BLK 16                 // timesteps per staged block
#define NBLK (RNN_T / BLK)     // 128
#define CHF (BLK * 5)          // 80 floats per chain per block
#define WVF (4 * CHF)          // 320 floats per wave per block
#define BLF (16 * CHF)         // 1280 floats per 256-thr block buffer

// tanh with pre-scaled argument: zs = 2*log2(e)*z ; tanh(z) = 1 - 2/(1 + 2^zs)
__device__ __forceinline__ float tanh_pre(float zs) {
    float e = __builtin_amdgcn_exp2f(zs);
    float r = __builtin_amdgcn_rcpf(e + 1.0f);
    return fmaf(-2.0f, r, 1.0f);
}

// Broadcast lane (group16_base | K) to all 16 lanes of the group.
// ds_swizzle BitMode: src = (lane & and) | or ; offset = (xor<<10)|(or<<5)|and.
template <int K>
__device__ __forceinline__ float bcast16(float v) {
    return __int_as_float(__builtin_amdgcn_ds_swizzle(__float_as_int(v), (K << 5) | 16));
}

template <int IDX>
__device__ __forceinline__ float getf(const float4 (&b)[5]) {
    constexpr int q = IDX >> 2, r = IDX & 3;
    if constexpr (r == 0) return b[q].x;
    else if constexpr (r == 1) return b[q].y;
    else if constexpr (r == 2) return b[q].z;
    else return b[q].w;
}

// Async global->LDS, 4B per lane, dest = wave-uniform base + lane*4.
__device__ __forceinline__ void async4(const float* src, float* dst) {
    __builtin_amdgcn_global_load_lds(
        (const __attribute__((address_space(1))) void*)src,
        (__attribute__((address_space(3))) void*)dst, 4, 0, 0);
}

// Fill one wave's 320-float region (4 chains x 80) = 5 DMA instructions.
__device__ __forceinline__ void fill_wave(float* dstWave, const float* (&src)[5],
                                          int adv) {
#pragma unroll
    for (int j = 0; j < 5; ++j) {
        async4(src[j], dstWave + j * 64);
        src[j] += adv;   // next block in fill order
    }
}

// One timestep: lane holds h[i]; gathers h[0..8] from lanes 0..8 of its group.
template <int U>
__device__ __forceinline__ void step16(const float4 (&buf)[5], float& h,
                                       const float (&W1)[5], const float (&W2)[9],
                                       const float bb) {
    float h0 = bcast16<0>(h), h1 = bcast16<1>(h), h2 = bcast16<2>(h);
    float h3 = bcast16<3>(h), h4 = bcast16<4>(h), h5 = bcast16<5>(h);
    float h6 = bcast16<6>(h), h7 = bcast16<7>(h), h8 = bcast16<8>(h);
    float a0 = fmaf(W1[0], getf<U * 5 + 0>(buf), bb);
    a0 = fmaf(W1[1], getf<U * 5 + 1>(buf), a0);
    a0 = fmaf(W1[2], getf<U * 5 + 2>(buf), a0);
    a0 = fmaf(W1[3], getf<U * 5 + 3>(buf), a0);
    a0 = fmaf(W1[4], getf<U * 5 + 4>(buf), a0);
    float a1 = W2[0] * h0;
    a1 = fmaf(W2[1], h1, a1);
    a1 = fmaf(W2[2], h2, a1);
    float a2 = W2[3] * h3;
    a2 = fmaf(W2[4], h4, a2);
    a2 = fmaf(W2[5], h5, a2);
    a0 = fmaf(W2[6], h6, a0);
    a1 = fmaf(W2[7], h7, a1);
    a2 = fmaf(W2[8], h8, a2);
    h = tanh_pre((a0 + a1) + a2);
}

__device__ __forceinline__ void ldfrag(float4 (&F)[5], const float* gbuf, int s4) {
    const float4* q = (const float4*)(gbuf + s4 * 20);   // 16B-aligned
#pragma unroll
    for (int v = 0; v < 5; ++v) F[v] = q[v];
}

template <bool FWD>
__device__ __forceinline__ void proc4(const float4 (&F)[5], float& h,
                                      const float (&W1)[5], const float (&W2)[9],
                                      const float bb) {
    if constexpr (FWD) {
        step16<0>(F, h, W1, W2, bb); step16<1>(F, h, W1, W2, bb);
        step16<2>(F, h, W1, W2, bb); step16<3>(F, h, W1, W2, bb);
    } else {
        step16<3>(F, h, W1, W2, bb); step16<2>(F, h, W1, W2, bb);
        step16<1>(F, h, W1, W2, bb); step16<0>(F, h, W1, W2, bb);
    }
}

// 16 steps from gbuf; optionally issue the next fill after the first frag read
// (so the vmcnt wait for THIS buffer lands before the new DMA is outstanding).
template <bool FWD, bool FILL>
__device__ __forceinline__ void compute_block(const float* gbuf, float& h,
        const float (&W1)[5], const float (&W2)[9], const float bb,
        float* fillDst, const float* (&src)[5], int adv) {
    float4 F[5];
    ldfrag(F, gbuf, FWD ? 0 : 3);
    if constexpr (FILL) fill_wave(fillDst, src, adv);
    proc4<FWD>(F, h, W1, W2, bb);
    ldfrag(F, gbuf, FWD ? 1 : 2);
    proc4<FWD>(F, h, W1, W2, bb);
    ldfrag(F, gbuf, FWD ? 2 : 1);
    proc4<FWD>(F, h, W1, W2, bb);
    ldfrag(F, gbuf, FWD ? 3 : 0);
    proc4<FWD>(F, h, W1, W2, bb);
}

// Triple-buffered rotation, statically unrolled x3 so the fill target is a
// distinct __shared__ object from the read source (alias-analysis friendly).
template <bool FWD>
__device__ __forceinline__ float run_all(const float* gA, const float* gB,
        const float* gC, float* wA, float* wB, float* wC,
        const float* (&src)[5], int adv,
        const float (&W1)[5], const float (&W2)[9], const float bb) {
    fill_wave(wA, src, adv);   // block 0
    fill_wave(wB, src, adv);   // block 1
    float h = 0.0f;
#pragma unroll 1
    for (int it = 0; it < 42; ++it) {   // blocks 3k, 3k+1, 3k+2 (0..125)
        compute_block<FWD, true >(gA, h, W1, W2, bb, wC, src, adv); // fill 3k+2
        compute_block<FWD, true >(gB, h, W1, W2, bb, wA, src, adv); // fill 3k+3
        compute_block<FWD, true >(gC, h, W1, W2, bb, wB, src, adv); // fill 3k+4
    }
    compute_block<FWD, false>(gA, h, W1, W2, bb, wC, src, adv);     // block 126
    compute_block<FWD, false>(gB, h, W1, W2, bb, wC, src, adv);     // block 127
    return h;
}

// 16 lanes per chain (lane i<9 owns h[i]); 4 chains/wave; 512x256 = 2048 waves
// = 2 waves/SIMD. x staged in LDS via async DMA (compiler cannot sink it).
__global__ __launch_bounds__(256, 2) void rnn1_kernel(
    const float* __restrict__ x,
    const float* __restrict__ w_ih_f, const float* __restrict__ w_hh_f,
    const float* __restrict__ b_ih_f, const float* __restrict__ b_hh_f,
    const float* __restrict__ w_ih_b, const float* __restrict__ w_hh_b,
    const float* __restrict__ b_ih_b, const float* __restrict__ b_hh_b,
    float* __restrict__ y)
{
    __shared__ __align__(16) float sA[BLF], sB[BLF], sC[BLF];   // 3 x 5120 B
    const float SC = 2.8853900817779268f; // 2*log2(e)
    const int tid    = threadIdx.x;
    const int group  = tid >> 4;          // 0..15
    const int lane16 = tid & 15;
    const int waveId = tid >> 6;          // 0..3
    const int lane   = tid & 63;
    const int chain  = blockIdx.x * 16 + group;   // 0..8191
    const int b      = chain & (RNN_B - 1);
    const int dir    = chain >> 12;               // uniform per block
    const int i      = (lane16 < 9) ? lane16 : 8;

    const float* __restrict__ wih = dir ? w_ih_b : w_ih_f;
    const float* __restrict__ whh = dir ? w_hh_b : w_hh_f;
    const float* __restrict__ bih = dir ? b_ih_b : b_ih_f;
    const float* __restrict__ bhh = dir ? b_hh_b : b_hh_f;

    float W1[5], W2[9];
#pragma unroll
    for (int d = 0; d < 5; ++d) W1[d] = wih[i * 5 + d] * SC;
#pragma unroll
    for (int k = 0; k < 9; ++k) W2[k] = whh[i * 9 + k] * SC;
    const float bb = (bih[i] + bhh[i]) * SC;

    // DMA source pointers: lane 'lane', instruction j covers wave-region word
    // idx = j*64+lane  ->  fill-chain gf = idx/80, in-block position p = idx%80.
    const float* src[5];
#pragma unroll
    for (int j = 0; j < 5; ++j) {
        const int idx = j * 64 + lane;            // 0..319
        const int gf  = idx / 80;                 // 0..3
        const int p   = idx - gf * 80;
        const int bf  = (blockIdx.x * 16 + waveId * 4 + gf) & (RNN_B - 1);
        src[j] = x + (size_t)bf * (RNN_T * 5) + (dir ? (NBLK - 1) * CHF : 0) + p;
    }
    const int adv = dir ? -CHF : CHF;

    float* wA = sA + waveId * WVF;
    float* wB = sB + waveId * WVF;
    float* wC = sC + waveId * WVF;
    const float* gA = sA + group * CHF;
    const float* gB = sB + group * CHF;
    const float* gC = sC + group * CHF;

    float h = dir ? run_all<false>(gA, gB, gC, wA, wB, wC, src, adv, W1, W2, bb)
                  : run_all<true >(gA, gB, gC, wA, wB, wC, src, adv, W1, W2, bb);

    if (lane16 < 9) y[b * 18 + dir * 9 + lane16] = h;
}

__global__ __launch_bounds__(256) void rnn2_kernel(
    const float* __restrict__ y,
    const float* __restrict__ w_ih2, const float* __restrict__ w_hh2,
    const float* __restrict__ b_ih2, const float* __restrict__ b_hh2,
    const float* __restrict__ w_out, const float* __restrict__ b_out,
    float* __restrict__ out)
{
    __shared__ float hist[8][25][32];   // 25.6 KB
    const float SC = 2.8853900817779268f;
    const int bl = threadIdx.x >> 5;    // 0..7 local batch
    const int i  = threadIdx.x & 31;    // component
    const int b  = blockIdx.x * 8 + bl;

    float wr[32];
#pragma unroll
    for (int k = 0; k < 32; ++k) wr[k] = w_hh2[i * 32 + k] * SC;
    const float bias = (b_ih2[i] + b_hh2[i]) * SC;

    const float* yb = y + b * 18;
    float z = bias;
#pragma unroll
    for (int k = 0; k < 18; ++k) z = fmaf(w_ih2[i * 18 + k] * SC, yb[k], z);
    hist[bl][0][i] = tanh_pre(z);
    __syncthreads();

    for (int t = 1; t < 25; ++t) {
        float zz = bias;
#pragma unroll
        for (int k = 0; k < 32; ++k) zz = fmaf(wr[k], hist[bl][t - 1][k], zz);
        hist[bl][t][i] = tanh_pre(zz);
        __syncthreads();
    }

    for (int e = threadIdx.x; e < 600; e += 256) {
        const int o  = e % 3;
        const int t  = (e / 3) % 25;
        const int b2 = e / 75;
        float acc = b_out[o];
#pragma unroll
        for (int k = 0; k < 32; ++k) acc = fmaf(w_out[o * 32 + k], hist[b2][t][k], acc);
        out[((size_t)(blockIdx.x * 8 + b2) * 25 + t) * 3 + o] = acc;
    }
}

extern "C" void kernel_launch(void* const* d_in, const int* in_sizes, int n_in,
                              void* d_out, int out_size, void* d_ws, size_t ws_size,
                              hipStream_t stream) {
    const float* x      = (const float*)d_in[0];
    const float* w_ih_f = (const float*)d_in[1];
    const float* w_hh_f = (const float*)d_in[2];
    const float* b_ih_f = (const float*)d_in[3];
    const float* b_hh_f = (const float*)d_in[4];
    const float* w_ih_b = (const float*)d_in[5];
    const float* w_hh_b = (const float*)d_in[6];
    const float* b_ih_b = (const float*)d_in[7];
    const float* b_hh_b = (const float*)d_in[8];
    const float* w_ih2  = (const float*)d_in[9];
    const float* w_hh2  = (const float*)d_in[10];
    const float* b_ih2  = (const float*)d_in[11];
    const float* b_hh2  = (const float*)d_in[12];
    const float* w_out  = (const float*)d_in[13];
    const float* b_out  = (const float*)d_in[14];

    float* y = (float*)d_ws;                 // [B][18] intermediate

    rnn1_kernel<<<dim3(512), dim3(256), 0, stream>>>(
        x, w_ih_f, w_hh_f, b_ih_f, b_hh_f,
        w_ih_b, w_hh_b, b_ih_b, b_hh_b, y);

    rnn2_kernel<<<dim3(RNN_B / 8), dim3(256), 0, stream>>>(
        y, w_ih2, w_hh2, b_ih2, b_hh2, w_out, b_out, (float*)d_out);
}

// Round 6
// 511.526 us; speedup vs baseline: 1.2651x; 1.1100x over previous
//
#include <hip/hip_runtime.h>

#define RNN_T 2048
#define RNN_B 4096
#define BLK 16                 // timesteps per staged block
#define NBLK (RNN_T / BLK)     // 128
#define CHF (BLK * 5)          // 80 floats per chain per block
#define WVF (4 * CHF)          // 320 floats per wave per block
#define BLF (16 * CHF)         // 1280 floats per 256-thr block buffer

// tanh with pre-scaled argument: zs = 2*log2(e)*z ; tanh(z) = 1 - 2/(1 + 2^zs)
__device__ __forceinline__ float tanh_pre(float zs) {
    float e = __builtin_amdgcn_exp2f(zs);
    float r = __builtin_amdgcn_rcpf(e + 1.0f);
    return fmaf(-2.0f, r, 1.0f);
}

// DPP row rotate-right by R within each 16-lane row: dst lane i <- src lane (i-R) mod 16.
// dpp_ctrl row_ror:R = 0x120 + R. VALU-pipe cross-lane (no LDS crossbar use).
template <int R>
__device__ __forceinline__ float rot16(float v) {
    if constexpr (R == 0) return v;
    else return __int_as_float(__builtin_amdgcn_update_dpp(
        0, __float_as_int(v), 0x120 + R, 0xf, 0xf, true));
}

template <int IDX>
__device__ __forceinline__ float getf(const float4 (&b)[5]) {
    constexpr int q = IDX >> 2, r = IDX & 3;
    if constexpr (r == 0) return b[q].x;
    else if constexpr (r == 1) return b[q].y;
    else if constexpr (r == 2) return b[q].z;
    else return b[q].w;
}

// Async global->LDS, 4B per lane, dest = wave-uniform base + lane*4.
__device__ __forceinline__ void async4(const float* src, float* dst) {
    __builtin_amdgcn_global_load_lds(
        (const __attribute__((address_space(1))) void*)src,
        (__attribute__((address_space(3))) void*)dst, 4, 0, 0);
}

// Fill one wave's 320-float region (4 chains x 80) = 5 DMA instructions.
__device__ __forceinline__ void fill_wave(float* dstWave, const float* (&src)[5],
                                          int adv) {
#pragma unroll
    for (int j = 0; j < 5; ++j) {
        async4(src[j], dstWave + j * 64);
        src[j] += adv;   // next block in fill order
    }
}

// One timestep. Lane i<9 owns h[i]; lanes 9-15 hold exact 0 (zero weights keep
// them 0: tanh_pre(0)=0). h-matvec via 16-slot DPP ring, all on the VALU pipe.
template <int U>
__device__ __forceinline__ void step16(const float4 (&buf)[5], float& h,
                                       const float (&W1)[5], const float (&Wd)[16],
                                       const float bb) {
    // x part
    float a0 = fmaf(W1[0], getf<U * 5 + 0>(buf), bb);
    a0 = fmaf(W1[1], getf<U * 5 + 1>(buf), a0);
    a0 = fmaf(W1[2], getf<U * 5 + 2>(buf), a0);
    a0 = fmaf(W1[3], getf<U * 5 + 3>(buf), a0);
    a0 = fmaf(W1[4], getf<U * 5 + 4>(buf), a0);
    // h part: rotations all read the ORIGINAL h (independent -> ILP)
    float a1 = h * Wd[0];
    float a2 = rot16<1>(h) * Wd[1];
    float a3 = rot16<2>(h) * Wd[2];
    a1 = fmaf(rot16<3>(h),  Wd[3],  a1);
    a2 = fmaf(rot16<4>(h),  Wd[4],  a2);
    a3 = fmaf(rot16<5>(h),  Wd[5],  a3);
    a1 = fmaf(rot16<6>(h),  Wd[6],  a1);
    a2 = fmaf(rot16<7>(h),  Wd[7],  a2);
    a3 = fmaf(rot16<8>(h),  Wd[8],  a3);
    a1 = fmaf(rot16<9>(h),  Wd[9],  a1);
    a2 = fmaf(rot16<10>(h), Wd[10], a2);
    a3 = fmaf(rot16<11>(h), Wd[11], a3);
    a1 = fmaf(rot16<12>(h), Wd[12], a1);
    a2 = fmaf(rot16<13>(h), Wd[13], a2);
    a3 = fmaf(rot16<14>(h), Wd[14], a3);
    a0 = fmaf(rot16<15>(h), Wd[15], a0);
    h = tanh_pre((a0 + a1) + (a2 + a3));
}

__device__ __forceinline__ void ldfrag(float4 (&F)[5], const float* gbuf, int s4) {
    const float4* q = (const float4*)(gbuf + s4 * 20);   // 16B-aligned
#pragma unroll
    for (int v = 0; v < 5; ++v) F[v] = q[v];
}

template <bool FWD>
__device__ __forceinline__ void proc4(const float4 (&F)[5], float& h,
                                      const float (&W1)[5], const float (&Wd)[16],
                                      const float bb) {
    if constexpr (FWD) {
        step16<0>(F, h, W1, Wd, bb); step16<1>(F, h, W1, Wd, bb);
        step16<2>(F, h, W1, Wd, bb); step16<3>(F, h, W1, Wd, bb);
    } else {
        step16<3>(F, h, W1, Wd, bb); step16<2>(F, h, W1, Wd, bb);
        step16<1>(F, h, W1, Wd, bb); step16<0>(F, h, W1, Wd, bb);
    }
}

// 16 steps from gbuf; optionally issue the next fill after the first frag read.
template <bool FWD, bool FILL>
__device__ __forceinline__ void compute_block(const float* gbuf, float& h,
        const float (&W1)[5], const float (&Wd)[16], const float bb,
        float* fillDst, const float* (&src)[5], int adv) {
    float4 F[5];
    ldfrag(F, gbuf, FWD ? 0 : 3);
    if constexpr (FILL) fill_wave(fillDst, src, adv);
    proc4<FWD>(F, h, W1, Wd, bb);
    ldfrag(F, gbuf, FWD ? 1 : 2);
    proc4<FWD>(F, h, W1, Wd, bb);
    ldfrag(F, gbuf, FWD ? 2 : 1);
    proc4<FWD>(F, h, W1, Wd, bb);
    ldfrag(F, gbuf, FWD ? 3 : 0);
    proc4<FWD>(F, h, W1, Wd, bb);
}

// Triple-buffered rotation, statically unrolled x3 (distinct __shared__ objects).
template <bool FWD>
__device__ __forceinline__ float run_all(const float* gA, const float* gB,
        const float* gC, float* wA, float* wB, float* wC,
        const float* (&src)[5], int adv,
        const float (&W1)[5], const float (&Wd)[16], const float bb) {
    fill_wave(wA, src, adv);   // block 0
    fill_wave(wB, src, adv);   // block 1
    float h = 0.0f;
#pragma unroll 1
    for (int it = 0; it < 42; ++it) {   // blocks 3k, 3k+1, 3k+2 (0..125)
        compute_block<FWD, true >(gA, h, W1, Wd, bb, wC, src, adv); // fill 3k+2
        compute_block<FWD, true >(gB, h, W1, Wd, bb, wA, src, adv); // fill 3k+3
        compute_block<FWD, true >(gC, h, W1, Wd, bb, wB, src, adv); // fill 3k+4
    }
    compute_block<FWD, false>(gA, h, W1, Wd, bb, wC, src, adv);     // block 126
    compute_block<FWD, false>(gB, h, W1, Wd, bb, wC, src, adv);     // block 127
    return h;
}

// 16 lanes per chain (lane i<9 owns h[i], 9-15 are zero ring slots);
// 4 chains/wave; 512x256 = 2048 waves = 2 waves/SIMD. x staged via LDS DMA.
__global__ __launch_bounds__(256, 2) void rnn1_kernel(
    const float* __restrict__ x,
    const float* __restrict__ w_ih_f, const float* __restrict__ w_hh_f,
    const float* __restrict__ b_ih_f, const float* __restrict__ b_hh_f,
    const float* __restrict__ w_ih_b, const float* __restrict__ w_hh_b,
    const float* __restrict__ b_ih_b, const float* __restrict__ b_hh_b,
    float* __restrict__ y)
{
    __shared__ __align__(16) float sA[BLF], sB[BLF], sC[BLF];   // 3 x 5120 B
    const float SC = 2.8853900817779268f; // 2*log2(e)
    const int tid    = threadIdx.x;
    const int group  = tid >> 4;          // 0..15
    const int lane16 = tid & 15;
    const int waveId = tid >> 6;          // 0..3
    const int lane   = tid & 63;
    const int chain  = blockIdx.x * 16 + group;   // 0..8191
    const int b      = chain & (RNN_B - 1);
    const int dir    = chain >> 12;               // uniform per block

    const float* __restrict__ wih = dir ? w_ih_b : w_ih_f;
    const float* __restrict__ whh = dir ? w_hh_b : w_hh_f;
    const float* __restrict__ bih = dir ? b_ih_b : b_ih_f;
    const float* __restrict__ bhh = dir ? b_hh_b : b_hh_f;

    // Lane-masked weights: lanes 9-15 get all-zero weights/bias -> h stays 0.
    const int   li  = (lane16 < 9) ? lane16 : 0;
    const float msk = (lane16 < 9) ? SC : 0.0f;
    float W1[5], Wd[16];
#pragma unroll
    for (int d = 0; d < 5; ++d) W1[d] = wih[li * 5 + d] * msk;
#pragma unroll
    for (int r = 0; r < 16; ++r) {
        const int k  = (lane16 - r) & 15;          // value index arriving at slot r
        const int ks = (k < 9) ? k : 0;
        const float m2 = (k < 9) ? msk : 0.0f;
        Wd[r] = whh[li * 9 + ks] * m2;
    }
    const float bb = (bih[li] + bhh[li]) * msk;

    // DMA source pointers: instruction j covers wave-region word idx = j*64+lane.
    const float* src[5];
#pragma unroll
    for (int j = 0; j < 5; ++j) {
        const int idx = j * 64 + lane;            // 0..319
        const int gf  = idx / 80;                 // 0..3
        const int p   = idx - gf * 80;
        const int bf  = (blockIdx.x * 16 + waveId * 4 + gf) & (RNN_B - 1);
        src[j] = x + (size_t)bf * (RNN_T * 5) + (dir ? (NBLK - 1) * CHF : 0) + p;
    }
    const int adv = dir ? -CHF : CHF;

    float* wA = sA + waveId * WVF;
    float* wB = sB + waveId * WVF;
    float* wC = sC + waveId * WVF;
    const float* gA = sA + group * CHF;
    const float* gB = sB + group * CHF;
    const float* gC = sC + group * CHF;

    float h = dir ? run_all<false>(gA, gB, gC, wA, wB, wC, src, adv, W1, Wd, bb)
                  : run_all<true >(gA, gB, gC, wA, wB, wC, src, adv, W1, Wd, bb);

    if (lane16 < 9) y[b * 18 + dir * 9 + lane16] = h;
}

__global__ __launch_bounds__(256) void rnn2_kernel(
    const float* __restrict__ y,
    const float* __restrict__ w_ih2, const float* __restrict__ w_hh2,
    const float* __restrict__ b_ih2, const float* __restrict__ b_hh2,
    const float* __restrict__ w_out, const float* __restrict__ b_out,
    float* __restrict__ out)
{
    __shared__ float hist[8][25][32];   // 25.6 KB
    const float SC = 2.8853900817779268f;
    const int bl = threadIdx.x >> 5;    // 0..7 local batch
    const int i  = threadIdx.x & 31;    // component
    const int b  = blockIdx.x * 8 + bl;

    float wr[32];
#pragma unroll
    for (int k = 0; k < 32; ++k) wr[k] = w_hh2[i * 32 + k] * SC;
    const float bias = (b_ih2[i] + b_hh2[i]) * SC;

    const float* yb = y + b * 18;
    float z = bias;
#pragma unroll
    for (int k = 0; k < 18; ++k) z = fmaf(w_ih2[i * 18 + k] * SC, yb[k], z);
    hist[bl][0][i] = tanh_pre(z);
    __syncthreads();

    for (int t = 1; t < 25; ++t) {
        float zz = bias;
#pragma unroll
        for (int k = 0; k < 32; ++k) zz = fmaf(wr[k], hist[bl][t - 1][k], zz);
        hist[bl][t][i] = tanh_pre(zz);
        __syncthreads();
    }

    for (int e = threadIdx.x; e < 600; e += 256) {
        const int o  = e % 3;
        const int t  = (e / 3) % 25;
        const int b2 = e / 75;
        float acc = b_out[o];
#pragma unroll
        for (int k = 0; k < 32; ++k) acc = fmaf(w_out[o * 32 + k], hist[b2][t][k], acc);
        out[((size_t)(blockIdx.x * 8 + b2) * 25 + t) * 3 + o] = acc;
    }
}

extern "C" void kernel_launch(void* const* d_in, const int* in_sizes, int n_in,
                              void* d_out, int out_size, void* d_ws, size_t ws_size,
                              hipStream_t stream) {
    const float* x      = (const float*)d_in[0];
    const float* w_ih_f = (const float*)d_in[1];
    const float* w_hh_f = (const float*)d_in[2];
    const float* b_ih_f = (const float*)d_in[3];
    const float* b_hh_f = (const float*)d_in[4];
    const float* w_ih_b = (const float*)d_in[5];
    const float* w_hh_b = (const float*)d_in[6];
    const float* b_ih_b = (const float*)d_in[7];
    const float* b_hh_b = (const float*)d_in[8];
    const float* w_ih2  = (const float*)d_in[9];
    const float* w_hh2  = (const float*)d_in[10];
    const float* b_ih2  = (const float*)d_in[11];
    const float* b_hh2  = (const float*)d_in[12];
    const float* w_out  = (const float*)d_in[13];
    const float* b_out  = (const float*)d_in[14];

    float* y = (float*)d_ws;                 // [B][18] intermediate

    rnn1_kernel<<<dim3(512), dim3(256), 0, stream>>>(
        x, w_ih_f, w_hh_f, b_ih_f, b_hh_f,
        w_ih_b, w_hh_b, b_ih_b, b_hh_b, y);

    rnn2_kernel<<<dim3(RNN_B / 8), dim3(256), 0, stream>>>(
        y, w_ih2, w_hh2, b_ih2, b_hh2, w_out, b_out, (float*)d_out);
}

// Round 7
// 423.862 us; speedup vs baseline: 1.5268x; 1.2068x over previous
//
#include <hip/hip_runtime.h>

#define RNN_T 2048
#define RNN_B 4096
#define BLK 16                 // timesteps per staged block
#define NBLK (RNN_T / BLK)     // 128
#define CHF (BLK * 5)          // 80 floats per chain per block
#define WVF (4 * CHF)          // 320 floats per wave per block
#define BLF (16 * CHF)         // 1280 floats per 256-thr block buffer

// tanh with pre-scaled argument: zs = 2*log2(e)*z ; tanh(z) = 1 - 2/(1 + 2^zs)
__device__ __forceinline__ float tanh_pre(float zs) {
    float e = __builtin_amdgcn_exp2f(zs);
    float r = __builtin_amdgcn_rcpf(e + 1.0f);
    return fmaf(-2.0f, r, 1.0f);
}

// Async global->LDS, 4B per lane, dest = wave-uniform base + lane*4.
__device__ __forceinline__ void async4(const float* src, float* dst) {
    __builtin_amdgcn_global_load_lds(
        (const __attribute__((address_space(1))) void*)src,
        (__attribute__((address_space(3))) void*)dst, 4, 0, 0);
}

// Fill one wave's 320-float region (4 chains x 80) = 5 DMA instructions.
__device__ __forceinline__ void fill_wave(float* dstWave, const float* (&src)[5],
                                          int adv) {
#pragma unroll
    for (int j = 0; j < 5; ++j) {
        async4(src[j], dstWave + j * 64);
        src[j] += adv;   // next block in fill order
    }
}

// One timestep. Ring state per 16-lane group: lanes 0-8 = h[0..8],
// lanes 9-13 = x_t[0..4], lanes 14-15 = junk (zero-weighted everywhere).
// z_i = sum over 16 DPP rotations of W[r] * state[(i-r)&15]; W folds W2|W1|0.
// Ring is hand-fused v_fmac_f32_dpp (VOP2+DPP) so no separate mov_dpp exists.
__device__ __forceinline__ void stepr(float& h, float xn, const float (&W)[16],
                                      float bb, bool own) {
    float a0 = fmaf(h, W[0], bb);    // r=0 slot + bias
    float a1 = 0.0f, a2 = 0.0f;
    asm ("s_nop 1\n\t"
         "v_fmac_f32_dpp %0, %3, %4  row_ror:1  row_mask:0xf bank_mask:0xf\n\t"
         "v_fmac_f32_dpp %1, %3, %5  row_ror:2  row_mask:0xf bank_mask:0xf\n\t"
         "v_fmac_f32_dpp %2, %3, %6  row_ror:3  row_mask:0xf bank_mask:0xf\n\t"
         "v_fmac_f32_dpp %0, %3, %7  row_ror:4  row_mask:0xf bank_mask:0xf\n\t"
         "v_fmac_f32_dpp %1, %3, %8  row_ror:5  row_mask:0xf bank_mask:0xf\n\t"
         "v_fmac_f32_dpp %2, %3, %9  row_ror:6  row_mask:0xf bank_mask:0xf\n\t"
         "v_fmac_f32_dpp %0, %3, %10 row_ror:7  row_mask:0xf bank_mask:0xf\n\t"
         "v_fmac_f32_dpp %1, %3, %11 row_ror:8  row_mask:0xf bank_mask:0xf\n\t"
         "v_fmac_f32_dpp %2, %3, %12 row_ror:9  row_mask:0xf bank_mask:0xf\n\t"
         "v_fmac_f32_dpp %0, %3, %13 row_ror:10 row_mask:0xf bank_mask:0xf\n\t"
         "v_fmac_f32_dpp %1, %3, %14 row_ror:11 row_mask:0xf bank_mask:0xf\n\t"
         "v_fmac_f32_dpp %2, %3, %15 row_ror:12 row_mask:0xf bank_mask:0xf\n\t"
         "v_fmac_f32_dpp %0, %3, %16 row_ror:13 row_mask:0xf bank_mask:0xf\n\t"
         "v_fmac_f32_dpp %1, %3, %17 row_ror:14 row_mask:0xf bank_mask:0xf\n\t"
         "v_fmac_f32_dpp %2, %3, %18 row_ror:15 row_mask:0xf bank_mask:0xf"
         : "+v"(a0), "+v"(a1), "+v"(a2)
         : "v"(h), "v"(W[1]), "v"(W[2]), "v"(W[3]), "v"(W[4]), "v"(W[5]),
           "v"(W[6]), "v"(W[7]), "v"(W[8]), "v"(W[9]), "v"(W[10]), "v"(W[11]),
           "v"(W[12]), "v"(W[13]), "v"(W[14]), "v"(W[15]));
    const float z = (a0 + a1) + a2;
    const float t = tanh_pre(z);
    h = own ? t : xn;   // lanes 0-8: new h; lanes 9-15: next x (junk for 14-15)
}

// 16 steps from xc. Next-x values preloaded into registers at block entry
// (one wait point per block); last step's next-x comes from the next buffer.
template <bool FWD, bool FILL>
__device__ __forceinline__ void compute_block(const float* xc, const float* xnb,
        float& h, const float (&W)[16], float bb, bool own,
        float* fillDst, const float* (&src)[5], int adv) {
    float xn[16];
#pragma unroll
    for (int j = 0; j < 15; ++j) xn[j] = xc[FWD ? (j + 1) * 5 : (14 - j) * 5];
    xn[15] = xnb[FWD ? 0 : 75];
    if constexpr (FILL) fill_wave(fillDst, src, adv);
#pragma unroll
    for (int j = 0; j < 16; ++j) stepr(h, xn[j], W, bb, own);
}

// Triple-buffered rotation, statically unrolled x3 (distinct __shared__ objects).
template <bool FWD>
__device__ __forceinline__ float run_all(const float* xcA, const float* xcB,
        const float* xcC, float* wA, float* wB, float* wC,
        const float* (&src)[5], int adv,
        const float (&W)[16], float bb, bool own) {
    fill_wave(wA, src, adv);   // block 0
    fill_wave(wB, src, adv);   // block 1
    float h = own ? 0.0f : xcA[FWD ? 0 : 75];   // prime: h=0, x-lanes = first x
#pragma unroll 1
    for (int it = 0; it < 42; ++it) {   // blocks 3k, 3k+1, 3k+2 (0..125)
        compute_block<FWD, true >(xcA, xcB, h, W, bb, own, wC, src, adv);
        compute_block<FWD, true >(xcB, xcC, h, W, bb, own, wA, src, adv);
        compute_block<FWD, true >(xcC, xcA, h, W, bb, own, wB, src, adv);
    }
    compute_block<FWD, false>(xcA, xcB, h, W, bb, own, wC, src, adv); // 126
    compute_block<FWD, false>(xcB, xcB, h, W, bb, own, wC, src, adv); // 127 (dummy next)
    return h;
}

// 16 lanes per chain; 4 chains/wave; 512x256 = 2048 waves = 2 waves/SIMD.
__global__ __launch_bounds__(256, 2) void rnn1_kernel(
    const float* __restrict__ x,
    const float* __restrict__ w_ih_f, const float* __restrict__ w_hh_f,
    const float* __restrict__ b_ih_f, const float* __restrict__ b_hh_f,
    const float* __restrict__ w_ih_b, const float* __restrict__ w_hh_b,
    const float* __restrict__ b_ih_b, const float* __restrict__ b_hh_b,
    float* __restrict__ y)
{
    __shared__ __align__(16) float sA[BLF], sB[BLF], sC[BLF];   // 3 x 5120 B
    const float SC = 2.8853900817779268f; // 2*log2(e)
    const int tid    = threadIdx.x;
    const int group  = tid >> 4;          // 0..15
    const int lane16 = tid & 15;
    const int waveId = tid >> 6;          // 0..3
    const int lane   = tid & 63;
    const int chain  = blockIdx.x * 16 + group;   // 0..8191
    const int b      = chain & (RNN_B - 1);
    const int dir    = chain >> 12;               // uniform per block

    const float* __restrict__ wih = dir ? w_ih_b : w_ih_f;
    const float* __restrict__ whh = dir ? w_hh_b : w_hh_f;
    const float* __restrict__ bih = dir ? b_ih_b : b_ih_f;
    const float* __restrict__ bhh = dir ? b_hh_b : b_hh_f;

    // Slot weights: for output lane i, slot r carries source lane s=(i-r)&15:
    // s<9 -> W2[i][s]; s in [9,14) -> W1[i][s-9]; s>=14 -> 0. Lanes i>=9 all 0.
    const int   li  = (lane16 < 9) ? lane16 : 0;
    const float msk = (lane16 < 9) ? SC : 0.0f;
    const bool  own = (lane16 < 9);
    float W[16];
#pragma unroll
    for (int r = 0; r < 16; ++r) {
        const int s = (lane16 - r) & 15;
        float w = 0.0f;
        if (s < 9)       w = whh[li * 9 + s];
        else if (s < 14) w = wih[li * 5 + (s - 9)];
        W[r] = w * msk;
    }
    const float bb = (bih[li] + bhh[li]) * msk;

    // DMA source pointers: instruction j covers wave-region word idx = j*64+lane.
    const float* src[5];
#pragma unroll
    for (int j = 0; j < 5; ++j) {
        const int idx = j * 64 + lane;            // 0..319
        const int gf  = idx / 80;                 // 0..3
        const int p   = idx - gf * 80;
        const int bf  = (blockIdx.x * 16 + waveId * 4 + gf) & (RNN_B - 1);
        src[j] = x + (size_t)bf * (RNN_T * 5) + (dir ? (NBLK - 1) * CHF : 0) + p;
    }
    const int adv = dir ? -CHF : CHF;

    float* wA = sA + waveId * WVF;
    float* wB = sB + waveId * WVF;
    float* wC = sC + waveId * WVF;
    // Per-lane x-read pointer: lanes 9-13 read component (lane16-9), others [0].
    const int xoff = own ? 0 : ((lane16 < 14) ? (lane16 - 9) : 0);
    const float* xcA = sA + group * CHF + xoff;
    const float* xcB = sB + group * CHF + xoff;
    const float* xcC = sC + group * CHF + xoff;

    float h = dir ? run_all<false>(xcA, xcB, xcC, wA, wB, wC, src, adv, W, bb, own)
                  : run_all<true >(xcA, xcB, xcC, wA, wB, wC, src, adv, W, bb, own);

    if (lane16 < 9) y[b * 18 + dir * 9 + lane16] = h;
}

__global__ __launch_bounds__(256) void rnn2_kernel(
    const float* __restrict__ y,
    const float* __restrict__ w_ih2, const float* __restrict__ w_hh2,
    const float* __restrict__ b_ih2, const float* __restrict__ b_hh2,
    const float* __restrict__ w_out, const float* __restrict__ b_out,
    float* __restrict__ out)
{
    __shared__ float hist[8][25][32];   // 25.6 KB
    const float SC = 2.8853900817779268f;
    const int bl = threadIdx.x >> 5;    // 0..7 local batch
    const int i  = threadIdx.x & 31;    // component
    const int b  = blockIdx.x * 8 + bl;

    float wr[32];
#pragma unroll
    for (int k = 0; k < 32; ++k) wr[k] = w_hh2[i * 32 + k] * SC;
    const float bias = (b_ih2[i] + b_hh2[i]) * SC;

    const float* yb = y + b * 18;
    float z = bias;
#pragma unroll
    for (int k = 0; k < 18; ++k) z = fmaf(w_ih2[i * 18 + k] * SC, yb[k], z);
    hist[bl][0][i] = tanh_pre(z);
    __syncthreads();

    for (int t = 1; t < 25; ++t) {
        float zz = bias;
#pragma unroll
        for (int k = 0; k < 32; ++k) zz = fmaf(wr[k], hist[bl][t - 1][k], zz);
        hist[bl][t][i] = tanh_pre(zz);
        __syncthreads();
    }

    for (int e = threadIdx.x; e < 600; e += 256) {
        const int o  = e % 3;
        const int t  = (e / 3) % 25;
        const int b2 = e / 75;
        float acc = b_out[o];
#pragma unroll
        for (int k = 0; k < 32; ++k) acc = fmaf(w_out[o * 32 + k], hist[b2][t][k], acc);
        out[((size_t)(blockIdx.x * 8 + b2) * 25 + t) * 3 + o] = acc;
    }
}

extern "C" void kernel_launch(void* const* d_in, const int* in_sizes, int n_in,
                              void* d_out, int out_size, void* d_ws, size_t ws_size,
                              hipStream_t stream) {
    const float* x      = (const float*)d_in[0];
    const float* w_ih_f = (const float*)d_in[1];
    const float* w_hh_f = (const float*)d_in[2];
    const float* b_ih_f = (const float*)d_in[3];
    const float* b_hh_f = (const float*)d_in[4];
    const float* w_ih_b = (const float*)d_in[5];
    const float* w_hh_b = (const float*)d_in[6];
    const float* b_ih_b = (const float*)d_in[7];
    const float* b_hh_b = (const float*)d_in[8];
    const float* w_ih2  = (const float*)d_in[9];
    const float* w_hh2  = (const float*)d_in[10];
    const float* b_ih2  = (const float*)d_in[11];
    const float* b_hh2  = (const float*)d_in[12];
    const float* w_out  = (const float*)d_in[13];
    const float* b_out  = (const float*)d_in[14];

    float* y = (float*)d_ws;                 // [B][18] intermediate

    rnn1_kernel<<<dim3(512), dim3(256), 0, stream>>>(
        x, w_ih_f, w_hh_f, b_ih_f, b_hh_f,
        w_ih_b, w_hh_b, b_ih_b, b_hh_b, y);

    rnn2_kernel<<<dim3(RNN_B / 8), dim3(256), 0, stream>>>(
        y, w_ih2, w_hh2, b_ih2, b_hh2, w_out, b_out, (float*)d_out);
}